// Round 6
// baseline (660.789 us; speedup 1.0000x reference)
//
#include <hip/hip_runtime.h>
#include <stdint.h>

typedef unsigned short u16;
typedef __attribute__((ext_vector_type(8))) short bf16x8;
typedef __attribute__((ext_vector_type(4))) float f32x4;

__device__ __forceinline__ u16 f2bf(float f) {
  union { float f; uint32_t u; } v; v.f = f;
  uint32_t u = v.u;
  return (u16)((u + 0x7fffu + ((u >> 16) & 1u)) >> 16);
}

__device__ __forceinline__ void gl_lds16(const void* g, void* l) {
  __builtin_amdgcn_global_load_lds(
      (const __attribute__((address_space(1))) uint32_t*)g,
      (__attribute__((address_space(3))) uint32_t*)l, 16, 0, 0);
}

__constant__ int c_off[9] = {0, 1024, 1808, 2384, 2784, 3040, 3184, 3248, 3264};

// ---------------------------------------------------------------------------
// Elementwise f32 -> bf16 (float4/thread). Used for x-flatten and lA convert.
// ---------------------------------------------------------------------------
__global__ __launch_bounds__(256)
void x_to_bf16(const float* __restrict__ x, u16* __restrict__ Xb) {
  const int i = blockIdx.x * 256 + threadIdx.x;
  const float4 v = ((const float4*)x)[i];
  ushort4 o = make_ushort4(f2bf(v.x), f2bf(v.y), f2bf(v.z), f2bf(v.w));
  ((ushort4*)Xb)[i] = o;
}

// ---------------------------------------------------------------------------
// Implicit-GEMM conv weight scatter: Wct[o][k] (3328 x 512 bf16, pre-zeroed).
// One block per output column o.
// ---------------------------------------------------------------------------
__global__ __launch_bounds__(256)
void build_wc(const float* w1, const float* w2, const float* w3, const float* w4,
              const float* w5, const float* w6, const float* w7, const float* w8,
              const float* __restrict__ cb,
              u16* __restrict__ Wct, float* __restrict__ bias_c) {
  const int o = blockIdx.x;
  const int t = threadIdx.x;
  const float* ws[8] = {w1, w2, w3, w4, w5, w6, w7, w8};
  int kidx = 0;
  while (o >= c_off[kidx + 1]) ++kidx;
  const int ks = kidx + 1;
  const int s  = 8 - kidx;
  const int r  = o - c_off[kidx];
  const int f   = r / (s * s);
  const int rem = r - f * s * s;
  const int oi  = rem / s;
  const int oj  = rem - oi * s;
  const float* w = ws[kidx] + (size_t)f * 8 * ks * ks;
  u16* row = Wct + (size_t)o * 512;
  const int ne = 8 * ks * ks;
  for (int e = t; e < ne; e += 256) {
    const int c  = e / (ks * ks);
    const int er = e - c * ks * ks;
    const int di = er / ks;
    const int dj = er - di * ks;
    row[((oi + di) * 8 + (oj + dj)) * 8 + c] = f2bf(w[(c * ks + di) * ks + dj]);
  }
  if (t == 0) bias_c[o] = cb[kidx * 16 + f];
}

// ---------------------------------------------------------------------------
// Transpose + fp32->bf16: src (R x C) f32 -> dst (Cp x R) bf16, zero-fill
// rows >= C. grid = (Cp/64, R/64).
// ---------------------------------------------------------------------------
__global__ __launch_bounds__(256)
void transpose_bf16(const float* __restrict__ src, u16* __restrict__ dst,
                    int R, int C) {
  __shared__ float tile[64][65];
  const int t = threadIdx.x;
  const int rb = blockIdx.y << 6, cbs = blockIdx.x << 6;
  for (int i = 0; i < 16; ++i) {
    const int idx = t + (i << 8);
    const int r = idx >> 6, c = idx & 63;
    float v = 0.f;
    if (cbs + c < C) v = src[(size_t)(rb + r) * C + cbs + c];
    tile[r][c] = v;
  }
  __syncthreads();
  for (int i = 0; i < 16; ++i) {
    const int idx = t + (i << 8);
    const int c = idx >> 6, r = idx & 63;
    dst[(size_t)(cbs + c) * R + rb + r] = f2bf(tile[r][c]);
  }
}

// ---------------------------------------------------------------------------
// bf16 MFMA GEMM, 64x128 block tile, 4 waves (32x64 each), BK=64, dbuf LDS,
// XOR-swizzled (R3: conflict-free). Grid = (N/128, M/64).
// EPI 0: relu(acc + bias[n]) -> outf + outb                   [E stage]
// EPI 1: relu(acc + st_in[m][n]) -> outf + outb               [recurrent]
// EPI 2: acc + bias[n] -> outf, guarded n < nvalid            [output]
// EPI 3: relu(acc + bias[n]) -> outb only                     [conv feat]
// EPI 4: W_eff: wv=W[cg][rg]; (wv!=0 ? wv+2*acc : 0) -> outb  [LoRA+mask,
//        output written transposed; st_in reused as W f32 base]
// ---------------------------------------------------------------------------
template<int EPI>
__global__ __launch_bounds__(256)
void gemm128(const u16* __restrict__ A, int lda,
             const u16* __restrict__ Bt, int ldb, int K,
             const float* __restrict__ bias,
             const float* __restrict__ st_in, int st_ld,
             float* __restrict__ outf, int outf_ld,
             u16* __restrict__ outb, int outb_ld, int nvalid) {
  __shared__ __align__(16) u16 As[2][64 * 64];
  __shared__ __align__(16) u16 Bs[2][128 * 64];
  const int t = threadIdx.x;
  const int w = t >> 6, lane = t & 63;
  const int mb = blockIdx.y << 6, nb = blockIdx.x << 7;
  const int m0 = (w & 1) << 5, n0 = (w >> 1) << 6;
  const int lr = lane & 15, lq = lane >> 4;

  f32x4 acc[2][4] = {};

  const int nk = K >> 6;

  auto stage = [&](int kt, int buf) {
    const int kb = kt << 6;
    for (int i = 0; i < 2; ++i) {                 // A: 512 chunks (64 rows)
      const int c   = (w << 7) + (i << 6) + lane;
      const int row = c >> 3;
      const int kg  = (c & 7) ^ (row & 7);
      gl_lds16(A + (size_t)(mb + row) * lda + kb + (kg << 3),
               (char*)As[buf] + c * 16);
    }
    for (int i = 0; i < 4; ++i) {                 // B: 1024 chunks (128 rows)
      const int c   = (w << 8) + (i << 6) + lane;
      const int row = c >> 3;
      const int kg  = (c & 7) ^ (row & 7);
      gl_lds16(Bt + (size_t)(nb + row) * ldb + kb + (kg << 3),
               (char*)Bs[buf] + c * 16);
    }
  };

  stage(0, 0);
  for (int kt = 0; kt < nk; ++kt) {
    const int buf = kt & 1;
    __syncthreads();
    if (kt + 1 < nk) stage(kt + 1, buf ^ 1);
    for (int kk = 0; kk < 2; ++kk) {
      const int kg = (kk << 2) + lq;
      const int sw = (kg ^ (lr & 7)) << 3;
      bf16x8 af[2], bf[4];
      for (int i = 0; i < 2; ++i)
        af[i] = *(const bf16x8*)&As[buf][(m0 + (i << 4) + lr) * 64 + sw];
      for (int j = 0; j < 4; ++j)
        bf[j] = *(const bf16x8*)&Bs[buf][(n0 + (j << 4) + lr) * 64 + sw];
      for (int i = 0; i < 2; ++i)
        for (int j = 0; j < 4; ++j)
          acc[i][j] = __builtin_amdgcn_mfma_f32_16x16x32_bf16(af[i], bf[j], acc[i][j], 0, 0, 0);
    }
  }

  // epilogue: C/D layout col = lane&15, row = (lane>>4)*4 + reg
  for (int i = 0; i < 2; ++i) {
    for (int j = 0; j < 4; ++j) {
      const int cg = nb + n0 + (j << 4) + lr;
      for (int r = 0; r < 4; ++r) {
        const int rg = mb + m0 + (i << 4) + (lq << 2) + r;
        float v = acc[i][j][r];
        if (EPI == 0) {
          v += bias[cg];
          v = v > 0.f ? v : 0.f;
          outf[(size_t)rg * outf_ld + cg] = v;
          outb[(size_t)rg * outb_ld + cg] = f2bf(v);
        } else if (EPI == 1) {
          v += st_in[(size_t)rg * st_ld + cg];
          v = v > 0.f ? v : 0.f;
          outf[(size_t)rg * outf_ld + cg] = v;
          outb[(size_t)rg * outb_ld + cg] = f2bf(v);
        } else if (EPI == 2) {
          if (cg < nvalid)
            outf[(size_t)rg * outf_ld + cg] = v + bias[cg];
        } else if (EPI == 3) {
          v += bias[cg];
          v = v > 0.f ? v : 0.f;
          outb[(size_t)rg * outb_ld + cg] = f2bf(v);
        } else {
          const float wv = st_in[(size_t)cg * 4096 + rg];   // W transposed read
          outb[(size_t)rg * outb_ld + cg] =
              (wv != 0.f) ? f2bf(wv + 2.0f * v) : (u16)0;
        }
      }
    }
  }
}

// ---------------------------------------------------------------------------
// Single-wave 64x64 GEMM, triple-buffered LDS, NO barriers, explicit
// fine-grained vmcnt (R5 A/B experiment vs gemm128<1>): wave-private LDS means
// no __syncthreads -> no forced vmcnt(0) drain; prefetch depth 2 (48 KB LDS).
// Fixed geometry: lda=ldb=st_ld=out_ld=4096, K=4096. Recurrent epilogue.
// ---------------------------------------------------------------------------
__global__ __launch_bounds__(64)
void gemm_sw1(const u16* __restrict__ A, const u16* __restrict__ Bt,
              const float* __restrict__ st_in,
              float* __restrict__ outf, u16* __restrict__ outb) {
  __shared__ __align__(16) u16 As[3][64 * 64];
  __shared__ __align__(16) u16 Bs[3][64 * 64];
  const int lane = threadIdx.x;
  const int mb = blockIdx.y << 6, nb = blockIdx.x << 6;
  const int lr = lane & 15, lq = lane >> 4;

  f32x4 acc[4][4] = {};
  const int nk = 64;

  auto stage = [&](int kt, int buf) {
    const int kb = kt << 6;
    for (int i = 0; i < 8; ++i) {        // 512 chunks each for A and B
      const int c   = (i << 6) + lane;
      const int row = c >> 3;
      const int kg  = (c & 7) ^ (row & 7);
      gl_lds16(A + (size_t)(mb + row) * 4096 + kb + (kg << 3),
               (char*)As[buf] + c * 16);
      gl_lds16(Bt + (size_t)(nb + row) * 4096 + kb + (kg << 3),
               (char*)Bs[buf] + c * 16);
    }
  };

  stage(0, 0);
  stage(1, 1);
  for (int kt = 0; kt < nk; ++kt) {
    const int buf = kt % 3;
    if (kt + 2 < nk) {
      stage(kt + 2, (kt + 2) % 3);
      // drain tile kt's 16 loads; keep kt+1's and kt+2's 32 in flight
      asm volatile("s_waitcnt vmcnt(32)" ::: "memory");
    } else if (kt + 1 < nk) {
      asm volatile("s_waitcnt vmcnt(16)" ::: "memory");
    } else {
      asm volatile("s_waitcnt vmcnt(0)" ::: "memory");
    }
    for (int kk = 0; kk < 2; ++kk) {
      const int kg = (kk << 2) + lq;
      const int sw = (kg ^ (lr & 7)) << 3;
      bf16x8 af[4], bf[4];
      for (int i = 0; i < 4; ++i)
        af[i] = *(const bf16x8*)&As[buf][((i << 4) + lr) * 64 + sw];
      for (int j = 0; j < 4; ++j)
        bf[j] = *(const bf16x8*)&Bs[buf][((j << 4) + lr) * 64 + sw];
      for (int i = 0; i < 4; ++i)
        for (int j = 0; j < 4; ++j)
          acc[i][j] = __builtin_amdgcn_mfma_f32_16x16x32_bf16(af[i], bf[j], acc[i][j], 0, 0, 0);
    }
  }

  for (int i = 0; i < 4; ++i) {
    for (int j = 0; j < 4; ++j) {
      const int cg = nb + (j << 4) + lr;
      for (int r = 0; r < 4; ++r) {
        const int rg = mb + (i << 4) + (lq << 2) + r;
        float v = acc[i][j][r] + st_in[(size_t)rg * 4096 + cg];
        v = v > 0.f ? v : 0.f;
        outf[(size_t)rg * 4096 + cg] = v;
        outb[(size_t)rg * 4096 + cg] = f2bf(v);
      }
    }
  }
}

// ---------------------------------------------------------------------------
extern "C" void kernel_launch(void* const* d_in, const int* in_sizes, int n_in,
                              void* d_out, int out_size, void* d_ws, size_t ws_size,
                              hipStream_t stream) {
  const float* x     = (const float*)d_in[0];
  const float* cw[8];
  for (int i = 0; i < 8; ++i) cw[i] = (const float*)d_in[1 + i];
  const float* convb = (const float*)d_in[9];
  const float* W     = (const float*)d_in[10];
  const float* lA    = (const float*)d_in[11];
  const float* lB    = (const float*)d_in[12];
  const float* ip_w  = (const float*)d_in[13];
  const float* ip_b  = (const float*)d_in[14];
  const float* out_w = (const float*)d_in[15];
  const float* out_b = (const float*)d_in[16];
  float* out = (float*)d_out;

  char* p = (char*)d_ws;
  u16* feat   = (u16*)p;  p += (size_t)1024 * 3328 * 2;   // lda 3328 (N padded)
  u16* ip_wt  = (u16*)p;  p += (size_t)1024 * 3264 * 2;
  u16* out_wt = (u16*)p;  p += (size_t)2048 * 1024 * 2;
  u16* Wt     = (u16*)p;  p += (size_t)4096 * 4096 * 2;
  float* st_f[2];
  st_f[0] = (float*)p;    p += (size_t)1024 * 4096 * 4;
  st_f[1] = (float*)p;    p += (size_t)1024 * 4096 * 4;
  u16* st_b[2];
  st_b[0] = (u16*)p;      p += (size_t)1024 * 4096 * 2;
  st_b[1] = (u16*)p;      p += (size_t)1024 * 4096 * 2;

  // Prep buffers alias st_f[1] (16 MB): all consumed before t=1 writes it.
  char* q = (char*)st_f[1];
  u16* Xb       = (u16*)q;  q += (size_t)1024 * 512 * 2;
  u16* Wct      = (u16*)q;  q += (size_t)3328 * 512 * 2;
  float* bias_c = (float*)q; q += (size_t)3328 * 4;
  u16* lBt      = (u16*)q;  q += (size_t)4096 * 64 * 2;   // lB transposed bf16
  u16* lAb      = (u16*)q;  q += (size_t)4096 * 64 * 2;   // lA bf16

  // --- conv prep ---
  x_to_bf16<<<512, 256, 0, stream>>>(x, Xb);
  hipMemsetAsync(Wct, 0, (size_t)3328 * 512 * 2, stream);
  hipMemsetAsync(bias_c, 0, (size_t)3328 * 4, stream);
  build_wc<<<3264, 256, 0, stream>>>(cw[0], cw[1], cw[2], cw[3],
                                     cw[4], cw[5], cw[6], cw[7], convb, Wct, bias_c);

  // --- weight transposes + LoRA prep ---
  transpose_bf16<<<dim3(16, 51), 256, 0, stream>>>(ip_w, ip_wt, 3264, 1024);
  transpose_bf16<<<dim3(32, 16), 256, 0, stream>>>(out_w, out_wt, 1024, 1968);
  transpose_bf16<<<dim3(64, 1), 256, 0, stream>>>(lB, lBt, 64, 4096);
  x_to_bf16<<<256, 256, 0, stream>>>(lA, lAb);   // 4096*64 f32 -> bf16

  // --- W_eff via MFMA (R5: replaces 62us VALU weff_kernel):
  // Wt[n][k] = (W[k][n]!=0) ? W[k][n] + 2*(lB^T @ lA^T)[n][k] : 0
  gemm128<4><<<dim3(32, 64), 256, 0, stream>>>(lBt, 64, lAb, 64, 64,
      nullptr, W, 0, nullptr, 0, Wt, 4096, 4096);

  hipMemsetAsync(st_f[0], 0, (size_t)1024 * 4096 * 4, stream);
  hipMemsetAsync(st_b[0], 0, (size_t)1024 * 4096 * 2, stream);

  // --- conv as MFMA GEMM ---
  gemm128<3><<<dim3(26, 16), 256, 0, stream>>>(Xb, 512, Wct, 512, 512,
      bias_c, nullptr, 0, nullptr, 0, feat, 3328, 3328);

  // t=0: state = relu(E_pad)
  gemm128<0><<<dim3(8, 16), 256, 0, stream>>>(feat, 3328, ip_wt, 3264, 3264,
      ip_b, nullptr, 0, st_f[0], 4096, st_b[0], 4096, 1024);

  // t=1..4: state = relu(state + state @ W_eff); A/B test:
  // ts=1,2 -> single-wave pipelined kernel; ts=3,4 -> R4 gemm128<1>
  for (int ts = 1; ts <= 4; ++ts) {
    const int cur = (ts - 1) & 1, nxt = ts & 1;
    if (ts <= 2) {
      gemm_sw1<<<dim3(64, 16), 64, 0, stream>>>(st_b[cur], Wt,
          st_f[cur], st_f[nxt], st_b[nxt]);
    } else {
      gemm128<1><<<dim3(32, 16), 256, 0, stream>>>(st_b[cur], 4096, Wt, 4096, 4096,
          nullptr, st_f[cur], 4096, st_f[nxt], 4096, st_b[nxt], 4096, 4096);
    }
  }

  // output: state[:, 3072:] @ out_w + out_b
  gemm128<2><<<dim3(16, 16), 256, 0, stream>>>(st_b[0] + 3072, 4096, out_wt, 1024, 1024,
      out_b, nullptr, 0, out, 1968, nullptr, 0, 1968);
}

// Round 7
// 499.036 us; speedup vs baseline: 1.3241x; 1.3241x over previous
//
#include <hip/hip_runtime.h>
#include <stdint.h>

typedef unsigned short u16;
typedef __attribute__((ext_vector_type(8))) short bf16x8;
typedef __attribute__((ext_vector_type(4))) float f32x4;

__device__ __forceinline__ u16 f2bf(float f) {
  union { float f; uint32_t u; } v; v.f = f;
  uint32_t u = v.u;
  return (u16)((u + 0x7fffu + ((u >> 16) & 1u)) >> 16);
}

__device__ __forceinline__ void gl_lds16(const void* g, void* l) {
  __builtin_amdgcn_global_load_lds(
      (const __attribute__((address_space(1))) uint32_t*)g,
      (__attribute__((address_space(3))) uint32_t*)l, 16, 0, 0);
}

__constant__ int c_off[9] = {0, 1024, 1808, 2384, 2784, 3040, 3184, 3248, 3264};

// ---------------------------------------------------------------------------
// Elementwise f32 -> bf16 (float4/thread). Used for x-flatten and lA convert.
// ---------------------------------------------------------------------------
__global__ __launch_bounds__(256)
void x_to_bf16(const float* __restrict__ x, u16* __restrict__ Xb) {
  const int i = blockIdx.x * 256 + threadIdx.x;
  const float4 v = ((const float4*)x)[i];
  ushort4 o = make_ushort4(f2bf(v.x), f2bf(v.y), f2bf(v.z), f2bf(v.w));
  ((ushort4*)Xb)[i] = o;
}

// ---------------------------------------------------------------------------
// Implicit-GEMM conv weight scatter: Wct[o][k] (3328 x 512 bf16, pre-zeroed).
// One block per output column o.
// ---------------------------------------------------------------------------
__global__ __launch_bounds__(256)
void build_wc(const float* w1, const float* w2, const float* w3, const float* w4,
              const float* w5, const float* w6, const float* w7, const float* w8,
              const float* __restrict__ cb,
              u16* __restrict__ Wct, float* __restrict__ bias_c) {
  const int o = blockIdx.x;
  const int t = threadIdx.x;
  const float* ws[8] = {w1, w2, w3, w4, w5, w6, w7, w8};
  int kidx = 0;
  while (o >= c_off[kidx + 1]) ++kidx;
  const int ks = kidx + 1;
  const int s  = 8 - kidx;
  const int r  = o - c_off[kidx];
  const int f   = r / (s * s);
  const int rem = r - f * s * s;
  const int oi  = rem / s;
  const int oj  = rem - oi * s;
  const float* w = ws[kidx] + (size_t)f * 8 * ks * ks;
  u16* row = Wct + (size_t)o * 512;
  const int ne = 8 * ks * ks;
  for (int e = t; e < ne; e += 256) {
    const int c  = e / (ks * ks);
    const int er = e - c * ks * ks;
    const int di = er / ks;
    const int dj = er - di * ks;
    row[((oi + di) * 8 + (oj + dj)) * 8 + c] = f2bf(w[(c * ks + di) * ks + dj]);
  }
  if (t == 0) bias_c[o] = cb[kidx * 16 + f];
}

// ---------------------------------------------------------------------------
// Transpose + fp32->bf16: src (R x C) f32 -> dst (Cp x R) bf16, zero-fill
// rows >= C. grid = (Cp/64, R/64).
// ---------------------------------------------------------------------------
__global__ __launch_bounds__(256)
void transpose_bf16(const float* __restrict__ src, u16* __restrict__ dst,
                    int R, int C) {
  __shared__ float tile[64][65];
  const int t = threadIdx.x;
  const int rb = blockIdx.y << 6, cbs = blockIdx.x << 6;
  for (int i = 0; i < 16; ++i) {
    const int idx = t + (i << 8);
    const int r = idx >> 6, c = idx & 63;
    float v = 0.f;
    if (cbs + c < C) v = src[(size_t)(rb + r) * C + cbs + c];
    tile[r][c] = v;
  }
  __syncthreads();
  for (int i = 0; i < 16; ++i) {
    const int idx = t + (i << 8);
    const int c = idx >> 6, r = idx & 63;
    dst[(size_t)(cbs + c) * R + rb + r] = f2bf(tile[r][c]);
  }
}

// ---------------------------------------------------------------------------
// bf16 MFMA GEMM, 64x128 block tile, 4 waves (32x64 each), BK=64, dbuf LDS,
// XOR-swizzled (R3: conflict-free). Grid = (N/128, M/64).
// EPI 0: relu(acc + bias[n]) -> outf + outb                   [E stage]
// EPI 1: relu(acc + st_in[m][n]) -> outf + outb               [recurrent]
// EPI 2: acc + bias[n] -> outf, guarded n < nvalid            [output]
// EPI 3: relu(acc + bias[n]) -> outb only                     [conv feat]
// EPI 4: W_eff: wv=W[cg][rg]; (wv!=0 ? wv+2*acc : 0) -> outb  [LoRA+mask,
//        output written transposed; st_in reused as W f32 base]
// ---------------------------------------------------------------------------
template<int EPI>
__global__ __launch_bounds__(256)
void gemm128(const u16* __restrict__ A, int lda,
             const u16* __restrict__ Bt, int ldb, int K,
             const float* __restrict__ bias,
             const float* __restrict__ st_in, int st_ld,
             float* __restrict__ outf, int outf_ld,
             u16* __restrict__ outb, int outb_ld, int nvalid) {
  __shared__ __align__(16) u16 As[2][64 * 64];
  __shared__ __align__(16) u16 Bs[2][128 * 64];
  const int t = threadIdx.x;
  const int w = t >> 6, lane = t & 63;
  const int mb = blockIdx.y << 6, nb = blockIdx.x << 7;
  const int m0 = (w & 1) << 5, n0 = (w >> 1) << 6;
  const int lr = lane & 15, lq = lane >> 4;

  f32x4 acc[2][4] = {};

  const int nk = K >> 6;

  auto stage = [&](int kt, int buf) {
    const int kb = kt << 6;
    for (int i = 0; i < 2; ++i) {                 // A: 512 chunks (64 rows)
      const int c   = (w << 7) + (i << 6) + lane;
      const int row = c >> 3;
      const int kg  = (c & 7) ^ (row & 7);
      gl_lds16(A + (size_t)(mb + row) * lda + kb + (kg << 3),
               (char*)As[buf] + c * 16);
    }
    for (int i = 0; i < 4; ++i) {                 // B: 1024 chunks (128 rows)
      const int c   = (w << 8) + (i << 6) + lane;
      const int row = c >> 3;
      const int kg  = (c & 7) ^ (row & 7);
      gl_lds16(Bt + (size_t)(nb + row) * ldb + kb + (kg << 3),
               (char*)Bs[buf] + c * 16);
    }
  };

  stage(0, 0);
  for (int kt = 0; kt < nk; ++kt) {
    const int buf = kt & 1;
    __syncthreads();
    if (kt + 1 < nk) stage(kt + 1, buf ^ 1);
    for (int kk = 0; kk < 2; ++kk) {
      const int kg = (kk << 2) + lq;
      const int sw = (kg ^ (lr & 7)) << 3;
      bf16x8 af[2], bf[4];
      for (int i = 0; i < 2; ++i)
        af[i] = *(const bf16x8*)&As[buf][(m0 + (i << 4) + lr) * 64 + sw];
      for (int j = 0; j < 4; ++j)
        bf[j] = *(const bf16x8*)&Bs[buf][(n0 + (j << 4) + lr) * 64 + sw];
      for (int i = 0; i < 2; ++i)
        for (int j = 0; j < 4; ++j)
          acc[i][j] = __builtin_amdgcn_mfma_f32_16x16x32_bf16(af[i], bf[j], acc[i][j], 0, 0, 0);
    }
  }

  // epilogue: C/D layout col = lane&15, row = (lane>>4)*4 + reg
  for (int i = 0; i < 2; ++i) {
    for (int j = 0; j < 4; ++j) {
      const int cg = nb + n0 + (j << 4) + lr;
      for (int r = 0; r < 4; ++r) {
        const int rg = mb + m0 + (i << 4) + (lq << 2) + r;
        float v = acc[i][j][r];
        if (EPI == 0) {
          v += bias[cg];
          v = v > 0.f ? v : 0.f;
          outf[(size_t)rg * outf_ld + cg] = v;
          outb[(size_t)rg * outb_ld + cg] = f2bf(v);
        } else if (EPI == 1) {
          v += st_in[(size_t)rg * st_ld + cg];
          v = v > 0.f ? v : 0.f;
          outf[(size_t)rg * outf_ld + cg] = v;
          outb[(size_t)rg * outb_ld + cg] = f2bf(v);
        } else if (EPI == 2) {
          if (cg < nvalid)
            outf[(size_t)rg * outf_ld + cg] = v + bias[cg];
        } else if (EPI == 3) {
          v += bias[cg];
          v = v > 0.f ? v : 0.f;
          outb[(size_t)rg * outb_ld + cg] = f2bf(v);
        } else {
          const float wv = st_in[(size_t)cg * 4096 + rg];   // W transposed read
          outb[(size_t)rg * outb_ld + cg] =
              (wv != 0.f) ? f2bf(wv + 2.0f * v) : (u16)0;
        }
      }
    }
  }
}

// ---------------------------------------------------------------------------
// R6 experiment: 64x64 block tile, 4 waves (32x32 each), BK=64, dbuf LDS
// (32 KB) -> grid (64,16) = 1024 blocks = 4 blocks/CU = 4 waves/SIMD (vs
// gemm128's 2). n-tile is the fast grid dim: same-n blocks spaced 64 apart
// (= 0 mod 8) share an XCD under round-robin dispatch -> B panel L2 reuse.
// Fixed recurrent geometry: lda=ldb=st_ld=out_ld=4096, K=4096, EPI 1.
// ---------------------------------------------------------------------------
__global__ __launch_bounds__(256)
void gemm64_rec(const u16* __restrict__ A, const u16* __restrict__ Bt,
                const float* __restrict__ st_in,
                float* __restrict__ outf, u16* __restrict__ outb) {
  __shared__ __align__(16) u16 As[2][64 * 64];
  __shared__ __align__(16) u16 Bs[2][64 * 64];
  const int t = threadIdx.x;
  const int w = t >> 6, lane = t & 63;
  const int mb = blockIdx.y << 6, nb = blockIdx.x << 6;
  const int m0 = (w & 1) << 5, n0 = (w >> 1) << 5;
  const int lr = lane & 15, lq = lane >> 4;

  f32x4 acc[2][2] = {};
  const int nk = 64;

  auto stage = [&](int kt, int buf) {
    const int kb = kt << 6;
    for (int i = 0; i < 2; ++i) {                 // 512 chunks each (64 rows)
      const int c   = (w << 7) + (i << 6) + lane;
      const int row = c >> 3;
      const int kg  = (c & 7) ^ (row & 7);
      gl_lds16(A  + (size_t)(mb + row) * 4096 + kb + (kg << 3),
               (char*)As[buf] + c * 16);
      gl_lds16(Bt + (size_t)(nb + row) * 4096 + kb + (kg << 3),
               (char*)Bs[buf] + c * 16);
    }
  };

  stage(0, 0);
  for (int kt = 0; kt < nk; ++kt) {
    const int buf = kt & 1;
    __syncthreads();
    if (kt + 1 < nk) stage(kt + 1, buf ^ 1);
    for (int kk = 0; kk < 2; ++kk) {
      const int kg = (kk << 2) + lq;
      const int sw = (kg ^ (lr & 7)) << 3;
      bf16x8 af[2], bf[2];
      for (int i = 0; i < 2; ++i)
        af[i] = *(const bf16x8*)&As[buf][(m0 + (i << 4) + lr) * 64 + sw];
      for (int j = 0; j < 2; ++j)
        bf[j] = *(const bf16x8*)&Bs[buf][(n0 + (j << 4) + lr) * 64 + sw];
      for (int i = 0; i < 2; ++i)
        for (int j = 0; j < 2; ++j)
          acc[i][j] = __builtin_amdgcn_mfma_f32_16x16x32_bf16(af[i], bf[j], acc[i][j], 0, 0, 0);
    }
  }

  for (int i = 0; i < 2; ++i) {
    for (int j = 0; j < 2; ++j) {
      const int cg = nb + n0 + (j << 4) + lr;
      for (int r = 0; r < 4; ++r) {
        const int rg = mb + m0 + (i << 4) + (lq << 2) + r;
        float v = acc[i][j][r] + st_in[(size_t)rg * 4096 + cg];
        v = v > 0.f ? v : 0.f;
        outf[(size_t)rg * 4096 + cg] = v;
        outb[(size_t)rg * 4096 + cg] = f2bf(v);
      }
    }
  }
}

// ---------------------------------------------------------------------------
extern "C" void kernel_launch(void* const* d_in, const int* in_sizes, int n_in,
                              void* d_out, int out_size, void* d_ws, size_t ws_size,
                              hipStream_t stream) {
  const float* x     = (const float*)d_in[0];
  const float* cw[8];
  for (int i = 0; i < 8; ++i) cw[i] = (const float*)d_in[1 + i];
  const float* convb = (const float*)d_in[9];
  const float* W     = (const float*)d_in[10];
  const float* lA    = (const float*)d_in[11];
  const float* lB    = (const float*)d_in[12];
  const float* ip_w  = (const float*)d_in[13];
  const float* ip_b  = (const float*)d_in[14];
  const float* out_w = (const float*)d_in[15];
  const float* out_b = (const float*)d_in[16];
  float* out = (float*)d_out;

  char* p = (char*)d_ws;
  u16* feat   = (u16*)p;  p += (size_t)1024 * 3328 * 2;   // lda 3328 (N padded)
  u16* ip_wt  = (u16*)p;  p += (size_t)1024 * 3264 * 2;
  u16* out_wt = (u16*)p;  p += (size_t)2048 * 1024 * 2;
  u16* Wt     = (u16*)p;  p += (size_t)4096 * 4096 * 2;
  float* st_f[2];
  st_f[0] = (float*)p;    p += (size_t)1024 * 4096 * 4;
  st_f[1] = (float*)p;    p += (size_t)1024 * 4096 * 4;
  u16* st_b[2];
  st_b[0] = (u16*)p;      p += (size_t)1024 * 4096 * 2;
  st_b[1] = (u16*)p;      p += (size_t)1024 * 4096 * 2;

  // Prep buffers alias st_f[1] (16 MB): all consumed before t=1 writes it.
  char* q = (char*)st_f[1];
  u16* Xb       = (u16*)q;  q += (size_t)1024 * 512 * 2;
  u16* Wct      = (u16*)q;  q += (size_t)3328 * 512 * 2;
  float* bias_c = (float*)q; q += (size_t)3328 * 4;
  u16* lBt      = (u16*)q;  q += (size_t)4096 * 64 * 2;   // lB transposed bf16
  u16* lAb      = (u16*)q;  q += (size_t)4096 * 64 * 2;   // lA bf16

  // --- conv prep ---
  x_to_bf16<<<512, 256, 0, stream>>>(x, Xb);
  hipMemsetAsync(Wct, 0, (size_t)3328 * 512 * 2, stream);
  hipMemsetAsync(bias_c, 0, (size_t)3328 * 4, stream);
  build_wc<<<3264, 256, 0, stream>>>(cw[0], cw[1], cw[2], cw[3],
                                     cw[4], cw[5], cw[6], cw[7], convb, Wct, bias_c);

  // --- weight transposes + LoRA prep ---
  transpose_bf16<<<dim3(16, 51), 256, 0, stream>>>(ip_w, ip_wt, 3264, 1024);
  transpose_bf16<<<dim3(32, 16), 256, 0, stream>>>(out_w, out_wt, 1024, 1968);
  transpose_bf16<<<dim3(64, 1), 256, 0, stream>>>(lB, lBt, 64, 4096);
  x_to_bf16<<<256, 256, 0, stream>>>(lA, lAb);   // 4096*64 f32 -> bf16

  // --- W_eff via MFMA (R5 win): Wt[n][k] = mask * (W + 2*lA@lB), transposed
  gemm128<4><<<dim3(32, 64), 256, 0, stream>>>(lBt, 64, lAb, 64, 64,
      nullptr, W, 0, nullptr, 0, Wt, 4096, 4096);

  hipMemsetAsync(st_f[0], 0, (size_t)1024 * 4096 * 4, stream);
  hipMemsetAsync(st_b[0], 0, (size_t)1024 * 4096 * 2, stream);

  // --- conv as MFMA GEMM ---
  gemm128<3><<<dim3(26, 16), 256, 0, stream>>>(Xb, 512, Wct, 512, 512,
      bias_c, nullptr, 0, nullptr, 0, feat, 3328, 3328);

  // t=0: state = relu(E_pad)
  gemm128<0><<<dim3(8, 16), 256, 0, stream>>>(feat, 3328, ip_wt, 3264, 3264,
      ip_b, nullptr, 0, st_f[0], 4096, st_b[0], 4096, 1024);

  // t=1..4: state = relu(state + state @ W_eff); A/B:
  // ts=1,2 -> gemm64_rec (4 waves/SIMD); ts=3,4 -> gemm128<1> (2 waves/SIMD)
  for (int ts = 1; ts <= 4; ++ts) {
    const int cur = (ts - 1) & 1, nxt = ts & 1;
    if (ts <= 2) {
      gemm64_rec<<<dim3(64, 16), 256, 0, stream>>>(st_b[cur], Wt,
          st_f[cur], st_f[nxt], st_b[nxt]);
    } else {
      gemm128<1><<<dim3(32, 16), 256, 0, stream>>>(st_b[cur], 4096, Wt, 4096, 4096,
          nullptr, st_f[cur], 4096, st_f[nxt], 4096, st_b[nxt], 4096, 4096);
    }
  }

  // output: state[:, 3072:] @ out_w + out_b
  gemm128<2><<<dim3(16, 16), 256, 0, stream>>>(st_b[0] + 3072, 4096, out_wt, 1024, 1024,
      out_b, nullptr, 0, out, 1968, nullptr, 0, 1968);
}

// Round 8
// 487.985 us; speedup vs baseline: 1.3541x; 1.0226x over previous
//
#include <hip/hip_runtime.h>
#include <stdint.h>

typedef unsigned short u16;
typedef __attribute__((ext_vector_type(8))) short bf16x8;
typedef __attribute__((ext_vector_type(4))) float f32x4;

__device__ __forceinline__ u16 f2bf(float f) {
  union { float f; uint32_t u; } v; v.f = f;
  uint32_t u = v.u;
  return (u16)((u + 0x7fffu + ((u >> 16) & 1u)) >> 16);
}

__device__ __forceinline__ void gl_lds16(const void* g, void* l) {
  __builtin_amdgcn_global_load_lds(
      (const __attribute__((address_space(1))) uint32_t*)g,
      (__attribute__((address_space(3))) uint32_t*)l, 16, 0, 0);
}

__constant__ int c_off[9] = {0, 1024, 1808, 2384, 2784, 3040, 3184, 3248, 3264};

// ---------------------------------------------------------------------------
// Elementwise f32 -> bf16 (float4/thread).
// ---------------------------------------------------------------------------
__global__ __launch_bounds__(256)
void x_to_bf16(const float* __restrict__ x, u16* __restrict__ Xb) {
  const int i = blockIdx.x * 256 + threadIdx.x;
  const float4 v = ((const float4*)x)[i];
  ushort4 o = make_ushort4(f2bf(v.x), f2bf(v.y), f2bf(v.z), f2bf(v.w));
  ((ushort4*)Xb)[i] = o;
}

// ---------------------------------------------------------------------------
// Implicit-GEMM conv weight scatter: Wct[o][k] (3328 x 512 bf16, pre-zeroed).
// ---------------------------------------------------------------------------
__global__ __launch_bounds__(256)
void build_wc(const float* w1, const float* w2, const float* w3, const float* w4,
              const float* w5, const float* w6, const float* w7, const float* w8,
              const float* __restrict__ cb,
              u16* __restrict__ Wct, float* __restrict__ bias_c) {
  const int o = blockIdx.x;
  const int t = threadIdx.x;
  const float* ws[8] = {w1, w2, w3, w4, w5, w6, w7, w8};
  int kidx = 0;
  while (o >= c_off[kidx + 1]) ++kidx;
  const int ks = kidx + 1;
  const int s  = 8 - kidx;
  const int r  = o - c_off[kidx];
  const int f   = r / (s * s);
  const int rem = r - f * s * s;
  const int oi  = rem / s;
  const int oj  = rem - oi * s;
  const float* w = ws[kidx] + (size_t)f * 8 * ks * ks;
  u16* row = Wct + (size_t)o * 512;
  const int ne = 8 * ks * ks;
  for (int e = t; e < ne; e += 256) {
    const int c  = e / (ks * ks);
    const int er = e - c * ks * ks;
    const int di = er / ks;
    const int dj = er - di * ks;
    row[((oi + di) * 8 + (oj + dj)) * 8 + c] = f2bf(w[(c * ks + di) * ks + dj]);
  }
  if (t == 0) bias_c[o] = cb[kidx * 16 + f];
}

// ---------------------------------------------------------------------------
// Transpose + fp32->bf16: src (R x C) f32 -> dst (Cp x R) bf16.
// ---------------------------------------------------------------------------
__global__ __launch_bounds__(256)
void transpose_bf16(const float* __restrict__ src, u16* __restrict__ dst,
                    int R, int C) {
  __shared__ float tile[64][65];
  const int t = threadIdx.x;
  const int rb = blockIdx.y << 6, cbs = blockIdx.x << 6;
  for (int i = 0; i < 16; ++i) {
    const int idx = t + (i << 8);
    const int r = idx >> 6, c = idx & 63;
    float v = 0.f;
    if (cbs + c < C) v = src[(size_t)(rb + r) * C + cbs + c];
    tile[r][c] = v;
  }
  __syncthreads();
  for (int i = 0; i < 16; ++i) {
    const int idx = t + (i << 8);
    const int c = idx >> 6, r = idx & 63;
    dst[(size_t)(cbs + c) * R + rb + r] = f2bf(tile[r][c]);
  }
}

// ---------------------------------------------------------------------------
// R8: dedicated W_eff kernel. Per 64x64 tile (grid x=n-tile, y=k-tile):
//   C[n][k] = sum_r lBt[n][r]*lA[k][r]  (MFMA, K=64; = (lA@lB)[k][n])
//   Wt[nb+n][kb+k] = (W[kb+k][nb+n]!=0) ? W + 2*C : 0
// W tile DMA'd with chunk-XOR swizzle -> conflict-free float4 combine reads;
// result transposed through padded LDS -> full 128B-row coalesced Wt writes
// (replaces gemm128<4> epilogue: 32B scattered stores, WRITE 46MB vs 32MB,
// 1.8 TB/s, 60us).
// ---------------------------------------------------------------------------
__global__ __launch_bounds__(256)
void weff2(const float* __restrict__ W, const u16* __restrict__ lBt,
           const u16* __restrict__ lAb, u16* __restrict__ Wt) {
  __shared__ __align__(16) u16 As_[64 * 64];    // lBt tile (n x r), swizzled
  __shared__ __align__(16) u16 Bs_[64 * 64];    // lA  tile (k x r), swizzled
  __shared__ __align__(16) float Wl[64 * 64];   // W tile [k][n], chunk-swizzled
  __shared__ u16 Ct[64 * 68];                   // out tile [n][k], padded
  const int t = threadIdx.x;
  const int w = t >> 6, lane = t & 63;
  const int nb = blockIdx.x << 6, kb = blockIdx.y << 6;
  const int m0 = (w & 1) << 5, n0 = (w >> 1) << 5;   // m: n-dim, n: k-dim
  const int lr = lane & 15, lq = lane >> 4;

  for (int i = 0; i < 2; ++i) {                 // 512 16B chunks each
    const int c   = (w << 7) + (i << 6) + lane;
    const int row = c >> 3;
    const int kg  = (c & 7) ^ (row & 7);
    gl_lds16(lBt + (size_t)(nb + row) * 64 + (kg << 3), (char*)As_ + c * 16);
    gl_lds16(lAb + (size_t)(kb + row) * 64 + (kg << 3), (char*)Bs_ + c * 16);
  }
  for (int i = 0; i < 4; ++i) {                 // W: 1024 16B chunks (4 floats)
    const int c   = (w << 8) + (i << 6) + lane;
    const int row = c >> 4;                     // k-local
    const int cc  = (c & 15) ^ (row & 15);      // swizzled n-chunk
    gl_lds16(W + (size_t)(kb + row) * 4096 + nb + (cc << 2), (char*)Wl + c * 16);
  }
  __syncthreads();

  f32x4 acc[2][2] = {};
  for (int kk = 0; kk < 2; ++kk) {
    const int kg = (kk << 2) + lq;
    const int sw = (kg ^ (lr & 7)) << 3;
    bf16x8 af[2], bf[2];
    for (int i = 0; i < 2; ++i)
      af[i] = *(const bf16x8*)&As_[(m0 + (i << 4) + lr) * 64 + sw];
    for (int j = 0; j < 2; ++j)
      bf[j] = *(const bf16x8*)&Bs_[(n0 + (j << 4) + lr) * 64 + sw];
    for (int i = 0; i < 2; ++i)
      for (int j = 0; j < 2; ++j)
        acc[i][j] = __builtin_amdgcn_mfma_f32_16x16x32_bf16(af[i], bf[j], acc[i][j], 0, 0, 0);
  }

  // combine: lane holds C[n=rg0+r][k=cg]; W value = Wl[cg][rg0+r] (swizzled)
  for (int i = 0; i < 2; ++i) {
    for (int j = 0; j < 2; ++j) {
      const int cg  = n0 + (j << 4) + lr;        // k-local
      const int rg0 = m0 + (i << 4) + (lq << 2); // n-local base
      const int ch  = (rg0 >> 2) ^ (cg & 15);
      const float4 wv4 = *(const float4*)&Wl[cg * 64 + (ch << 2)];
      const float wv[4] = {wv4.x, wv4.y, wv4.z, wv4.w};
      for (int r = 0; r < 4; ++r)
        Ct[(rg0 + r) * 68 + cg] =
            (wv[r] != 0.f) ? f2bf(wv[r] + 2.0f * acc[i][j][r]) : (u16)0;
    }
  }
  __syncthreads();

  // coalesced write-out: thread t -> Wt row nb+(t>>2), k-chunk (t&3)*16
  const int row = t >> 2, kp = (t & 3) << 4;
  u16* dst = Wt + (size_t)(nb + row) * 4096 + kb + kp;
  const u16* src = &Ct[row * 68 + kp];
  for (int i = 0; i < 4; ++i)
    *(ushort4*)(dst + (i << 2)) = *(const ushort4*)(src + (i << 2));
}

// ---------------------------------------------------------------------------
// bf16 MFMA GEMM, 64x128 block tile, 4 waves (32x64 each), BK=64, dbuf LDS,
// XOR-swizzled. Grid = (N/128, M/64).
// EPI 0: relu(acc + bias[n]) -> outf + outb                   [E stage]
// EPI 1: relu(acc + st_in[m][n]) -> outf + outb               [recurrent]
// EPI 2: acc + bias[n] -> outf, guarded n < nvalid            [output]
// EPI 3: relu(acc + bias[n]) -> outb only                     [conv feat]
// ---------------------------------------------------------------------------
template<int EPI>
__global__ __launch_bounds__(256)
void gemm128(const u16* __restrict__ A, int lda,
             const u16* __restrict__ Bt, int ldb, int K,
             const float* __restrict__ bias,
             const float* __restrict__ st_in, int st_ld,
             float* __restrict__ outf, int outf_ld,
             u16* __restrict__ outb, int outb_ld, int nvalid) {
  __shared__ __align__(16) u16 As[2][64 * 64];
  __shared__ __align__(16) u16 Bs[2][128 * 64];
  const int t = threadIdx.x;
  const int w = t >> 6, lane = t & 63;
  const int mb = blockIdx.y << 6, nb = blockIdx.x << 7;
  const int m0 = (w & 1) << 5, n0 = (w >> 1) << 6;
  const int lr = lane & 15, lq = lane >> 4;

  f32x4 acc[2][4] = {};
  const int nk = K >> 6;

  auto stage = [&](int kt, int buf) {
    const int kb = kt << 6;
    for (int i = 0; i < 2; ++i) {
      const int c   = (w << 7) + (i << 6) + lane;
      const int row = c >> 3;
      const int kg  = (c & 7) ^ (row & 7);
      gl_lds16(A + (size_t)(mb + row) * lda + kb + (kg << 3),
               (char*)As[buf] + c * 16);
    }
    for (int i = 0; i < 4; ++i) {
      const int c   = (w << 8) + (i << 6) + lane;
      const int row = c >> 3;
      const int kg  = (c & 7) ^ (row & 7);
      gl_lds16(Bt + (size_t)(nb + row) * ldb + kb + (kg << 3),
               (char*)Bs[buf] + c * 16);
    }
  };

  stage(0, 0);
  for (int kt = 0; kt < nk; ++kt) {
    const int buf = kt & 1;
    __syncthreads();
    if (kt + 1 < nk) stage(kt + 1, buf ^ 1);
    for (int kk = 0; kk < 2; ++kk) {
      const int kg = (kk << 2) + lq;
      const int sw = (kg ^ (lr & 7)) << 3;
      bf16x8 af[2], bf[4];
      for (int i = 0; i < 2; ++i)
        af[i] = *(const bf16x8*)&As[buf][(m0 + (i << 4) + lr) * 64 + sw];
      for (int j = 0; j < 4; ++j)
        bf[j] = *(const bf16x8*)&Bs[buf][(n0 + (j << 4) + lr) * 64 + sw];
      for (int i = 0; i < 2; ++i)
        for (int j = 0; j < 4; ++j)
          acc[i][j] = __builtin_amdgcn_mfma_f32_16x16x32_bf16(af[i], bf[j], acc[i][j], 0, 0, 0);
    }
  }

  for (int i = 0; i < 2; ++i) {
    for (int j = 0; j < 4; ++j) {
      const int cg = nb + n0 + (j << 4) + lr;
      for (int r = 0; r < 4; ++r) {
        const int rg = mb + m0 + (i << 4) + (lq << 2) + r;
        float v = acc[i][j][r];
        if (EPI == 0) {
          v += bias[cg];
          v = v > 0.f ? v : 0.f;
          outf[(size_t)rg * outf_ld + cg] = v;
          outb[(size_t)rg * outb_ld + cg] = f2bf(v);
        } else if (EPI == 1) {
          v += st_in[(size_t)rg * st_ld + cg];
          v = v > 0.f ? v : 0.f;
          outf[(size_t)rg * outf_ld + cg] = v;
          outb[(size_t)rg * outb_ld + cg] = f2bf(v);
        } else if (EPI == 2) {
          if (cg < nvalid)
            outf[(size_t)rg * outf_ld + cg] = v + bias[cg];
        } else {
          v += bias[cg];
          v = v > 0.f ? v : 0.f;
          outb[(size_t)rg * outb_ld + cg] = f2bf(v);
        }
      }
    }
  }
}

// ---------------------------------------------------------------------------
// R8 experiment: 64x128 tile, TRIPLE-buffered LDS (72 KB, still 2 blocks/CU),
// prefetch distance 2, raw s_barrier + fine-grained vmcnt instead of
// __syncthreads (hipBLASLt-style: never drain to 0 mid-loop). Each wave
// issues 6 gl_lds per stage; vmcnt(6) at iter top = "tile kt landed, tile
// kt+1 may remain in flight". Per-wave waits + s_barrier ensure the full
// tile is visible to all waves; WAR on buffer (kt+2)%3 is safe because all
// waves passed the barrier after consuming it (lgkm waits precede their
// MFMAs). Fixed recurrent geometry: lda=ldb=st_ld=4096, K=4096, EPI 1.
// ---------------------------------------------------------------------------
__global__ __launch_bounds__(256)
void gemm_tb(const u16* __restrict__ A, const u16* __restrict__ Bt,
             const float* __restrict__ st_in,
             float* __restrict__ outf, u16* __restrict__ outb) {
  __shared__ __align__(16) u16 As[3][64 * 64];
  __shared__ __align__(16) u16 Bs[3][128 * 64];
  const int t = threadIdx.x;
  const int w = t >> 6, lane = t & 63;
  const int mb = blockIdx.y << 6, nb = blockIdx.x << 7;
  const int m0 = (w & 1) << 5, n0 = (w >> 1) << 6;
  const int lr = lane & 15, lq = lane >> 4;

  f32x4 acc[2][4] = {};
  const int nk = 64;

  auto stage = [&](int kt, int buf) {
    const int kb = kt << 6;
    for (int i = 0; i < 2; ++i) {
      const int c   = (w << 7) + (i << 6) + lane;
      const int row = c >> 3;
      const int kg  = (c & 7) ^ (row & 7);
      gl_lds16(A + (size_t)(mb + row) * 4096 + kb + (kg << 3),
               (char*)As[buf] + c * 16);
    }
    for (int i = 0; i < 4; ++i) {
      const int c   = (w << 8) + (i << 6) + lane;
      const int row = c >> 3;
      const int kg  = (c & 7) ^ (row & 7);
      gl_lds16(Bt + (size_t)(nb + row) * 4096 + kb + (kg << 3),
               (char*)Bs[buf] + c * 16);
    }
  };

  stage(0, 0);
  stage(1, 1);
  for (int kt = 0; kt < nk; ++kt) {
    const int buf = kt % 3;
    if (kt + 1 < nk) {
      asm volatile("s_waitcnt vmcnt(6)" ::: "memory");   // tile kt landed
    } else {
      asm volatile("s_waitcnt vmcnt(0)" ::: "memory");
    }
    asm volatile("s_barrier" ::: "memory");
    if (kt + 2 < nk) stage(kt + 2, (kt + 2) % 3);
    for (int kk = 0; kk < 2; ++kk) {
      const int kg = (kk << 2) + lq;
      const int sw = (kg ^ (lr & 7)) << 3;
      bf16x8 af[2], bf[4];
      for (int i = 0; i < 2; ++i)
        af[i] = *(const bf16x8*)&As[buf][(m0 + (i << 4) + lr) * 64 + sw];
      for (int j = 0; j < 4; ++j)
        bf[j] = *(const bf16x8*)&Bs[buf][(n0 + (j << 4) + lr) * 64 + sw];
      for (int i = 0; i < 2; ++i)
        for (int j = 0; j < 4; ++j)
          acc[i][j] = __builtin_amdgcn_mfma_f32_16x16x32_bf16(af[i], bf[j], acc[i][j], 0, 0, 0);
    }
  }

  for (int i = 0; i < 2; ++i) {
    for (int j = 0; j < 4; ++j) {
      const int cg = nb + n0 + (j << 4) + lr;
      for (int r = 0; r < 4; ++r) {
        const int rg = mb + m0 + (i << 4) + (lq << 2) + r;
        float v = acc[i][j][r] + st_in[(size_t)rg * 4096 + cg];
        v = v > 0.f ? v : 0.f;
        outf[(size_t)rg * 4096 + cg] = v;
        outb[(size_t)rg * 4096 + cg] = f2bf(v);
      }
    }
  }
}

// ---------------------------------------------------------------------------
extern "C" void kernel_launch(void* const* d_in, const int* in_sizes, int n_in,
                              void* d_out, int out_size, void* d_ws, size_t ws_size,
                              hipStream_t stream) {
  const float* x     = (const float*)d_in[0];
  const float* cw[8];
  for (int i = 0; i < 8; ++i) cw[i] = (const float*)d_in[1 + i];
  const float* convb = (const float*)d_in[9];
  const float* W     = (const float*)d_in[10];
  const float* lA    = (const float*)d_in[11];
  const float* lB    = (const float*)d_in[12];
  const float* ip_w  = (const float*)d_in[13];
  const float* ip_b  = (const float*)d_in[14];
  const float* out_w = (const float*)d_in[15];
  const float* out_b = (const float*)d_in[16];
  float* out = (float*)d_out;

  char* p = (char*)d_ws;
  u16* feat   = (u16*)p;  p += (size_t)1024 * 3328 * 2;   // lda 3328 (N padded)
  u16* ip_wt  = (u16*)p;  p += (size_t)1024 * 3264 * 2;
  u16* out_wt = (u16*)p;  p += (size_t)2048 * 1024 * 2;
  u16* Wt     = (u16*)p;  p += (size_t)4096 * 4096 * 2;
  float* st_f[2];
  st_f[0] = (float*)p;    p += (size_t)1024 * 4096 * 4;
  st_f[1] = (float*)p;    p += (size_t)1024 * 4096 * 4;
  u16* st_b[2];
  st_b[0] = (u16*)p;      p += (size_t)1024 * 4096 * 2;
  st_b[1] = (u16*)p;      p += (size_t)1024 * 4096 * 2;

  // Prep buffers alias st_f[1] (16 MB): all consumed before t=1 writes it.
  char* q = (char*)st_f[1];
  u16* Xb       = (u16*)q;  q += (size_t)1024 * 512 * 2;
  u16* Wct      = (u16*)q;  q += (size_t)3328 * 512 * 2;
  float* bias_c = (float*)q; q += (size_t)3328 * 4;
  u16* lBt      = (u16*)q;  q += (size_t)4096 * 64 * 2;   // lB transposed bf16
  u16* lAb      = (u16*)q;  q += (size_t)4096 * 64 * 2;   // lA bf16

  // --- conv prep ---
  x_to_bf16<<<512, 256, 0, stream>>>(x, Xb);
  hipMemsetAsync(Wct, 0, (size_t)3328 * 512 * 2, stream);
  hipMemsetAsync(bias_c, 0, (size_t)3328 * 4, stream);
  build_wc<<<3264, 256, 0, stream>>>(cw[0], cw[1], cw[2], cw[3],
                                     cw[4], cw[5], cw[6], cw[7], convb, Wct, bias_c);

  // --- weight transposes + LoRA prep ---
  transpose_bf16<<<dim3(16, 51), 256, 0, stream>>>(ip_w, ip_wt, 3264, 1024);
  transpose_bf16<<<dim3(32, 16), 256, 0, stream>>>(out_w, out_wt, 1024, 1968);
  transpose_bf16<<<dim3(64, 1), 256, 0, stream>>>(lB, lBt, 64, 4096);
  x_to_bf16<<<256, 256, 0, stream>>>(lA, lAb);   // 4096*64 f32 -> bf16

  // --- W_eff (R8: dedicated kernel, coalesced read+write) ---
  weff2<<<dim3(64, 64), 256, 0, stream>>>(W, lBt, lAb, Wt);

  hipMemsetAsync(st_f[0], 0, (size_t)1024 * 4096 * 4, stream);
  hipMemsetAsync(st_b[0], 0, (size_t)1024 * 4096 * 2, stream);

  // --- conv as MFMA GEMM ---
  gemm128<3><<<dim3(26, 16), 256, 0, stream>>>(Xb, 512, Wct, 512, 512,
      bias_c, nullptr, 0, nullptr, 0, feat, 3328, 3328);

  // t=0: state = relu(E_pad)
  gemm128<0><<<dim3(8, 16), 256, 0, stream>>>(feat, 3328, ip_wt, 3264, 3264,
      ip_b, nullptr, 0, st_f[0], 4096, st_b[0], 4096, 1024);

  // t=1..4: state = relu(state + state @ W_eff); A/B:
  // ts=1,2 -> gemm_tb (triple-buffer + raw barrier); ts=3,4 -> gemm128<1>
  for (int ts = 1; ts <= 4; ++ts) {
    const int cur = (ts - 1) & 1, nxt = ts & 1;
    if (ts <= 2) {
      gemm_tb<<<dim3(32, 16), 256, 0, stream>>>(st_b[cur], Wt,
          st_f[cur], st_f[nxt], st_b[nxt]);
    } else {
      gemm128<1><<<dim3(32, 16), 256, 0, stream>>>(st_b[cur], 4096, Wt, 4096, 4096,
          nullptr, st_f[cur], 4096, st_f[nxt], 4096, st_b[nxt], 4096, 4096);
    }
  }

  // output: state[:, 3072:] @ out_w + out_b
  gemm128<2><<<dim3(16, 16), 256, 0, stream>>>(st_b[0] + 3072, 4096, out_wt, 1024, 1024,
      out_b, nullptr, 0, out, 1968, nullptr, 0, 1968);
}

// Round 9
// 469.267 us; speedup vs baseline: 1.4081x; 1.0399x over previous
//
#include <hip/hip_runtime.h>
#include <stdint.h>

typedef unsigned short u16;
typedef __attribute__((ext_vector_type(8))) short bf16x8;
typedef __attribute__((ext_vector_type(4))) float f32x4;

__device__ __forceinline__ u16 f2bf(float f) {
  union { float f; uint32_t u; } v; v.f = f;
  uint32_t u = v.u;
  return (u16)((u + 0x7fffu + ((u >> 16) & 1u)) >> 16);
}

__device__ __forceinline__ void gl_lds16(const void* g, void* l) {
  __builtin_amdgcn_global_load_lds(
      (const __attribute__((address_space(1))) uint32_t*)g,
      (__attribute__((address_space(3))) uint32_t*)l, 16, 0, 0);
}

__constant__ int c_off[9] = {0, 1024, 1808, 2384, 2784, 3040, 3184, 3248, 3264};

// ---------------------------------------------------------------------------
// Elementwise f32 -> bf16 (float4/thread).
// ---------------------------------------------------------------------------
__global__ __launch_bounds__(256)
void x_to_bf16(const float* __restrict__ x, u16* __restrict__ Xb) {
  const int i = blockIdx.x * 256 + threadIdx.x;
  const float4 v = ((const float4*)x)[i];
  ushort4 o = make_ushort4(f2bf(v.x), f2bf(v.y), f2bf(v.z), f2bf(v.w));
  ((ushort4*)Xb)[i] = o;
}

// ---------------------------------------------------------------------------
// Implicit-GEMM conv weight scatter: Wct[o][k] (3328 x 512 bf16, pre-zeroed).
// ---------------------------------------------------------------------------
__global__ __launch_bounds__(256)
void build_wc(const float* w1, const float* w2, const float* w3, const float* w4,
              const float* w5, const float* w6, const float* w7, const float* w8,
              const float* __restrict__ cb,
              u16* __restrict__ Wct, float* __restrict__ bias_c) {
  const int o = blockIdx.x;
  const int t = threadIdx.x;
  const float* ws[8] = {w1, w2, w3, w4, w5, w6, w7, w8};
  int kidx = 0;
  while (o >= c_off[kidx + 1]) ++kidx;
  const int ks = kidx + 1;
  const int s  = 8 - kidx;
  const int r  = o - c_off[kidx];
  const int f   = r / (s * s);
  const int rem = r - f * s * s;
  const int oi  = rem / s;
  const int oj  = rem - oi * s;
  const float* w = ws[kidx] + (size_t)f * 8 * ks * ks;
  u16* row = Wct + (size_t)o * 512;
  const int ne = 8 * ks * ks;
  for (int e = t; e < ne; e += 256) {
    const int c  = e / (ks * ks);
    const int er = e - c * ks * ks;
    const int di = er / ks;
    const int dj = er - di * ks;
    row[((oi + di) * 8 + (oj + dj)) * 8 + c] = f2bf(w[(c * ks + di) * ks + dj]);
  }
  if (t == 0) bias_c[o] = cb[kidx * 16 + f];
}

// ---------------------------------------------------------------------------
// Transpose + fp32->bf16: src (R x C) f32 -> dst (Cp x R) bf16.
// ---------------------------------------------------------------------------
__global__ __launch_bounds__(256)
void transpose_bf16(const float* __restrict__ src, u16* __restrict__ dst,
                    int R, int C) {
  __shared__ float tile[64][65];
  const int t = threadIdx.x;
  const int rb = blockIdx.y << 6, cbs = blockIdx.x << 6;
  for (int i = 0; i < 16; ++i) {
    const int idx = t + (i << 8);
    const int r = idx >> 6, c = idx & 63;
    float v = 0.f;
    if (cbs + c < C) v = src[(size_t)(rb + r) * C + cbs + c];
    tile[r][c] = v;
  }
  __syncthreads();
  for (int i = 0; i < 16; ++i) {
    const int idx = t + (i << 8);
    const int c = idx >> 6, r = idx & 63;
    dst[(size_t)(cbs + c) * R + rb + r] = f2bf(tile[r][c]);
  }
}

// ---------------------------------------------------------------------------
// W_eff kernel (R8 win, ~18us): per 64x64 tile, MFMA LoRA product + masked
// combine with W + transpose through padded LDS -> coalesced Wt writes.
// ---------------------------------------------------------------------------
__global__ __launch_bounds__(256)
void weff2(const float* __restrict__ W, const u16* __restrict__ lBt,
           const u16* __restrict__ lAb, u16* __restrict__ Wt) {
  __shared__ __align__(16) u16 As_[64 * 64];
  __shared__ __align__(16) u16 Bs_[64 * 64];
  __shared__ __align__(16) float Wl[64 * 64];
  __shared__ u16 Ct[64 * 68];
  const int t = threadIdx.x;
  const int w = t >> 6, lane = t & 63;
  const int nb = blockIdx.x << 6, kb = blockIdx.y << 6;
  const int m0 = (w & 1) << 5, n0 = (w >> 1) << 5;
  const int lr = lane & 15, lq = lane >> 4;

  for (int i = 0; i < 2; ++i) {
    const int c   = (w << 7) + (i << 6) + lane;
    const int row = c >> 3;
    const int kg  = (c & 7) ^ (row & 7);
    gl_lds16(lBt + (size_t)(nb + row) * 64 + (kg << 3), (char*)As_ + c * 16);
    gl_lds16(lAb + (size_t)(kb + row) * 64 + (kg << 3), (char*)Bs_ + c * 16);
  }
  for (int i = 0; i < 4; ++i) {
    const int c   = (w << 8) + (i << 6) + lane;
    const int row = c >> 4;
    const int cc  = (c & 15) ^ (row & 15);
    gl_lds16(W + (size_t)(kb + row) * 4096 + nb + (cc << 2), (char*)Wl + c * 16);
  }
  __syncthreads();

  f32x4 acc[2][2] = {};
  for (int kk = 0; kk < 2; ++kk) {
    const int kg = (kk << 2) + lq;
    const int sw = (kg ^ (lr & 7)) << 3;
    bf16x8 af[2], bf[2];
    for (int i = 0; i < 2; ++i)
      af[i] = *(const bf16x8*)&As_[(m0 + (i << 4) + lr) * 64 + sw];
    for (int j = 0; j < 2; ++j)
      bf[j] = *(const bf16x8*)&Bs_[(n0 + (j << 4) + lr) * 64 + sw];
    for (int i = 0; i < 2; ++i)
      for (int j = 0; j < 2; ++j)
        acc[i][j] = __builtin_amdgcn_mfma_f32_16x16x32_bf16(af[i], bf[j], acc[i][j], 0, 0, 0);
  }

  for (int i = 0; i < 2; ++i) {
    for (int j = 0; j < 2; ++j) {
      const int cg  = n0 + (j << 4) + lr;
      const int rg0 = m0 + (i << 4) + (lq << 2);
      const int ch  = (rg0 >> 2) ^ (cg & 15);
      const float4 wv4 = *(const float4*)&Wl[cg * 64 + (ch << 2)];
      const float wv[4] = {wv4.x, wv4.y, wv4.z, wv4.w};
      for (int r = 0; r < 4; ++r)
        Ct[(rg0 + r) * 68 + cg] =
            (wv[r] != 0.f) ? f2bf(wv[r] + 2.0f * acc[i][j][r]) : (u16)0;
    }
  }
  __syncthreads();

  const int row = t >> 2, kp = (t & 3) << 4;
  u16* dst = Wt + (size_t)(nb + row) * 4096 + kb + kp;
  const u16* src = &Ct[row * 68 + kp];
  for (int i = 0; i < 4; ++i)
    *(ushort4*)(dst + (i << 2)) = *(const ushort4*)(src + (i << 2));
}

// ---------------------------------------------------------------------------
// bf16 MFMA GEMM, 64x128 block tile, 4 waves (32x64 each), BK=64, dbuf LDS,
// XOR-swizzled. Grid = (N/128, M/64). The proven workhorse (~570 TF).
// EPI 1: relu(acc + st_in[m][n]) -> outf + outb               [recurrent]
// EPI 2: acc + bias[n] -> outf, guarded n < nvalid            [output]
// EPI 3: relu(acc + bias[n]) -> outb only                     [conv feat]
// ---------------------------------------------------------------------------
template<int EPI>
__global__ __launch_bounds__(256)
void gemm128(const u16* __restrict__ A, int lda,
             const u16* __restrict__ Bt, int ldb, int K,
             const float* __restrict__ bias,
             const float* __restrict__ st_in, int st_ld,
             float* __restrict__ outf, int outf_ld,
             u16* __restrict__ outb, int outb_ld, int nvalid) {
  __shared__ __align__(16) u16 As[2][64 * 64];
  __shared__ __align__(16) u16 Bs[2][128 * 64];
  const int t = threadIdx.x;
  const int w = t >> 6, lane = t & 63;
  const int mb = blockIdx.y << 6, nb = blockIdx.x << 7;
  const int m0 = (w & 1) << 5, n0 = (w >> 1) << 6;
  const int lr = lane & 15, lq = lane >> 4;

  f32x4 acc[2][4] = {};
  const int nk = K >> 6;

  auto stage = [&](int kt, int buf) {
    const int kb = kt << 6;
    for (int i = 0; i < 2; ++i) {
      const int c   = (w << 7) + (i << 6) + lane;
      const int row = c >> 3;
      const int kg  = (c & 7) ^ (row & 7);
      gl_lds16(A + (size_t)(mb + row) * lda + kb + (kg << 3),
               (char*)As[buf] + c * 16);
    }
    for (int i = 0; i < 4; ++i) {
      const int c   = (w << 8) + (i << 6) + lane;
      const int row = c >> 3;
      const int kg  = (c & 7) ^ (row & 7);
      gl_lds16(Bt + (size_t)(nb + row) * ldb + kb + (kg << 3),
               (char*)Bs[buf] + c * 16);
    }
  };

  stage(0, 0);
  for (int kt = 0; kt < nk; ++kt) {
    const int buf = kt & 1;
    __syncthreads();
    if (kt + 1 < nk) stage(kt + 1, buf ^ 1);
    for (int kk = 0; kk < 2; ++kk) {
      const int kg = (kk << 2) + lq;
      const int sw = (kg ^ (lr & 7)) << 3;
      bf16x8 af[2], bf[4];
      for (int i = 0; i < 2; ++i)
        af[i] = *(const bf16x8*)&As[buf][(m0 + (i << 4) + lr) * 64 + sw];
      for (int j = 0; j < 4; ++j)
        bf[j] = *(const bf16x8*)&Bs[buf][(n0 + (j << 4) + lr) * 64 + sw];
      for (int i = 0; i < 2; ++i)
        for (int j = 0; j < 4; ++j)
          acc[i][j] = __builtin_amdgcn_mfma_f32_16x16x32_bf16(af[i], bf[j], acc[i][j], 0, 0, 0);
    }
  }

  for (int i = 0; i < 2; ++i) {
    for (int j = 0; j < 4; ++j) {
      const int cg = nb + n0 + (j << 4) + lr;
      for (int r = 0; r < 4; ++r) {
        const int rg = mb + m0 + (i << 4) + (lq << 2) + r;
        float v = acc[i][j][r];
        if (EPI == 1) {
          v += st_in[(size_t)rg * st_ld + cg];
          v = v > 0.f ? v : 0.f;
          outf[(size_t)rg * outf_ld + cg] = v;
          outb[(size_t)rg * outb_ld + cg] = f2bf(v);
        } else if (EPI == 2) {
          if (cg < nvalid)
            outf[(size_t)rg * outf_ld + cg] = v + bias[cg];
        } else {
          v += bias[cg];
          v = v > 0.f ? v : 0.f;
          outb[(size_t)rg * outb_ld + cg] = f2bf(v);
        }
      }
    }
  }
}

// ---------------------------------------------------------------------------
// R9: E-stage GEMM with split-K=2 (blockIdx.z). E was 128 blocks = 0.5/CU
// (half the CUs idle); z-split doubles to 256. Writes f32 partials; the
// combine kernel applies bias+relu+dual-store. K chunks: z=0 -> 26 iters
// from k=0, z=1 -> 25 iters from k=1664 (26+25 = 51 = 3264/64).
// ---------------------------------------------------------------------------
__global__ __launch_bounds__(256)
void gemm_e(const u16* __restrict__ A, const u16* __restrict__ Bt,
            float* __restrict__ part) {
  __shared__ __align__(16) u16 As[2][64 * 64];
  __shared__ __align__(16) u16 Bs[2][128 * 64];
  const int t = threadIdx.x;
  const int w = t >> 6, lane = t & 63;
  const int mb = blockIdx.y << 6, nb = blockIdx.x << 7;
  const int m0 = (w & 1) << 5, n0 = (w >> 1) << 6;
  const int lr = lane & 15, lq = lane >> 4;
  const int z = blockIdx.z;
  const int k0 = z ? 1664 : 0;
  const int nk = z ? 25 : 26;

  f32x4 acc[2][4] = {};

  auto stage = [&](int kt, int buf) {
    const int kb = k0 + (kt << 6);
    for (int i = 0; i < 2; ++i) {
      const int c   = (w << 7) + (i << 6) + lane;
      const int row = c >> 3;
      const int kg  = (c & 7) ^ (row & 7);
      gl_lds16(A + (size_t)(mb + row) * 3328 + kb + (kg << 3),
               (char*)As[buf] + c * 16);
    }
    for (int i = 0; i < 4; ++i) {
      const int c   = (w << 8) + (i << 6) + lane;
      const int row = c >> 3;
      const int kg  = (c & 7) ^ (row & 7);
      gl_lds16(Bt + (size_t)(nb + row) * 3264 + kb + (kg << 3),
               (char*)Bs[buf] + c * 16);
    }
  };

  stage(0, 0);
  for (int kt = 0; kt < nk; ++kt) {
    const int buf = kt & 1;
    __syncthreads();
    if (kt + 1 < nk) stage(kt + 1, buf ^ 1);
    for (int kk = 0; kk < 2; ++kk) {
      const int kg = (kk << 2) + lq;
      const int sw = (kg ^ (lr & 7)) << 3;
      bf16x8 af[2], bf[4];
      for (int i = 0; i < 2; ++i)
        af[i] = *(const bf16x8*)&As[buf][(m0 + (i << 4) + lr) * 64 + sw];
      for (int j = 0; j < 4; ++j)
        bf[j] = *(const bf16x8*)&Bs[buf][(n0 + (j << 4) + lr) * 64 + sw];
      for (int i = 0; i < 2; ++i)
        for (int j = 0; j < 4; ++j)
          acc[i][j] = __builtin_amdgcn_mfma_f32_16x16x32_bf16(af[i], bf[j], acc[i][j], 0, 0, 0);
    }
  }

  float* dst = part + (size_t)z * 1024 * 1024;
  for (int i = 0; i < 2; ++i)
    for (int j = 0; j < 4; ++j) {
      const int cg = nb + n0 + (j << 4) + lr;
      for (int r = 0; r < 4; ++r) {
        const int rg = mb + m0 + (i << 4) + (lq << 2) + r;
        dst[(size_t)rg * 1024 + cg] = acc[i][j][r];
      }
    }
}

// ---------------------------------------------------------------------------
// E combine: st = relu(Ep0 + Ep1 + bias), dual-store f32 + bf16 into the
// 4096-wide state buffers (cols < 1024). float4 per thread.
// ---------------------------------------------------------------------------
__global__ __launch_bounds__(256)
void e_combine(const float* __restrict__ part, const float* __restrict__ bias,
               float* __restrict__ st_f, u16* __restrict__ st_b) {
  const int i = (blockIdx.x * 256 + threadIdx.x) << 2;
  const int row = i >> 10, col = i & 1023;
  const float4 a = *(const float4*)&part[i];
  const float4 b = *(const float4*)&part[1024 * 1024 + i];
  const float4 bs = *(const float4*)&bias[col];
  float v[4] = {a.x + b.x + bs.x, a.y + b.y + bs.y,
                a.z + b.z + bs.z, a.w + b.w + bs.w};
  u16 o[4];
  for (int r = 0; r < 4; ++r) {
    v[r] = v[r] > 0.f ? v[r] : 0.f;
    o[r] = f2bf(v[r]);
  }
  *(float4*)&st_f[(size_t)row * 4096 + col] = make_float4(v[0], v[1], v[2], v[3]);
  *(ushort4*)&st_b[(size_t)row * 4096 + col] = make_ushort4(o[0], o[1], o[2], o[3]);
}

// ---------------------------------------------------------------------------
extern "C" void kernel_launch(void* const* d_in, const int* in_sizes, int n_in,
                              void* d_out, int out_size, void* d_ws, size_t ws_size,
                              hipStream_t stream) {
  const float* x     = (const float*)d_in[0];
  const float* cw[8];
  for (int i = 0; i < 8; ++i) cw[i] = (const float*)d_in[1 + i];
  const float* convb = (const float*)d_in[9];
  const float* W     = (const float*)d_in[10];
  const float* lA    = (const float*)d_in[11];
  const float* lB    = (const float*)d_in[12];
  const float* ip_w  = (const float*)d_in[13];
  const float* ip_b  = (const float*)d_in[14];
  const float* out_w = (const float*)d_in[15];
  const float* out_b = (const float*)d_in[16];
  float* out = (float*)d_out;

  char* p = (char*)d_ws;
  u16* feat   = (u16*)p;  p += (size_t)1024 * 3328 * 2;   // lda 3328 (N padded)
  u16* ip_wt  = (u16*)p;  p += (size_t)1024 * 3264 * 2;
  u16* out_wt = (u16*)p;  p += (size_t)2048 * 1024 * 2;
  u16* Wt     = (u16*)p;  p += (size_t)4096 * 4096 * 2;
  float* st_f[2];
  st_f[0] = (float*)p;    p += (size_t)1024 * 4096 * 4;
  st_f[1] = (float*)p;    p += (size_t)1024 * 4096 * 4;
  u16* st_b[2];
  st_b[0] = (u16*)p;      p += (size_t)1024 * 4096 * 2;
  st_b[1] = (u16*)p;      p += (size_t)1024 * 4096 * 2;

  // Prep buffers alias st_f[1] (16 MB): all consumed before ts=1 writes it.
  char* q = (char*)st_f[1];
  u16* Xb       = (u16*)q;  q += (size_t)1024 * 512 * 2;
  u16* Wct      = (u16*)q;  q += (size_t)3328 * 512 * 2;
  float* bias_c = (float*)q; q += (size_t)3328 * 4;
  u16* lBt      = (u16*)q;  q += (size_t)4096 * 64 * 2;
  u16* lAb      = (u16*)q;  q += (size_t)4096 * 64 * 2;
  q = (char*)st_f[1] + (size_t)6 * 1024 * 1024;
  float* Epart  = (float*)q;                               // 8 MB (2 x 4 MB)

  // --- conv prep ---
  x_to_bf16<<<512, 256, 0, stream>>>(x, Xb);
  hipMemsetAsync(Wct, 0, (size_t)3328 * 512 * 2, stream);
  hipMemsetAsync(bias_c, 0, (size_t)3328 * 4, stream);
  build_wc<<<3264, 256, 0, stream>>>(cw[0], cw[1], cw[2], cw[3],
                                     cw[4], cw[5], cw[6], cw[7], convb, Wct, bias_c);

  // --- weight transposes + LoRA prep ---
  transpose_bf16<<<dim3(16, 51), 256, 0, stream>>>(ip_w, ip_wt, 3264, 1024);
  transpose_bf16<<<dim3(32, 16), 256, 0, stream>>>(out_w, out_wt, 1024, 1968);
  transpose_bf16<<<dim3(64, 1), 256, 0, stream>>>(lB, lBt, 64, 4096);
  x_to_bf16<<<256, 256, 0, stream>>>(lA, lAb);

  // --- W_eff ---
  weff2<<<dim3(64, 64), 256, 0, stream>>>(W, lBt, lAb, Wt);

  hipMemsetAsync(st_f[0], 0, (size_t)1024 * 4096 * 4, stream);
  hipMemsetAsync(st_b[0], 0, (size_t)1024 * 4096 * 2, stream);

  // --- conv as MFMA GEMM ---
  gemm128<3><<<dim3(26, 16), 256, 0, stream>>>(Xb, 512, Wct, 512, 512,
      bias_c, nullptr, 0, nullptr, 0, feat, 3328, 3328);

  // t=0: state = relu(E_pad), E via split-K=2 + combine
  gemm_e<<<dim3(8, 16, 2), 256, 0, stream>>>(feat, ip_wt, Epart);
  e_combine<<<1024, 256, 0, stream>>>(Epart, ip_b, st_f[0], st_b[0]);

  // t=1..4: state = relu(state + state @ W_eff) — all gemm128<1> (R8: tb,
  // sw1, gemm64 all failed to beat it; shape-structural plateau ~570 TF)
  for (int ts = 1; ts <= 4; ++ts) {
    const int cur = (ts - 1) & 1, nxt = ts & 1;
    gemm128<1><<<dim3(32, 16), 256, 0, stream>>>(st_b[cur], 4096, Wt, 4096, 4096,
        nullptr, st_f[cur], 4096, st_f[nxt], 4096, st_b[nxt], 4096, 4096);
  }

  // output: state[:, 3072:] @ out_w + out_b
  gemm128<2><<<dim3(16, 16), 256, 0, stream>>>(st_b[0] + 3072, 4096, out_wt, 1024, 1024,
      out_b, nullptr, 0, out, 1968, nullptr, 0, 1968);
}

// Round 10
// 442.400 us; speedup vs baseline: 1.4936x; 1.0607x over previous
//
#include <hip/hip_runtime.h>
#include <stdint.h>

typedef unsigned short u16;
typedef __attribute__((ext_vector_type(8))) short bf16x8;
typedef __attribute__((ext_vector_type(4))) float f32x4;

__device__ __forceinline__ u16 f2bf(float f) {
  union { float f; uint32_t u; } v; v.f = f;
  uint32_t u = v.u;
  return (u16)((u + 0x7fffu + ((u >> 16) & 1u)) >> 16);
}

__device__ __forceinline__ void gl_lds16(const void* g, void* l) {
  __builtin_amdgcn_global_load_lds(
      (const __attribute__((address_space(1))) uint32_t*)g,
      (__attribute__((address_space(3))) uint32_t*)l, 16, 0, 0);
}

__constant__ int c_off[9] = {0, 1024, 1808, 2384, 2784, 3040, 3184, 3248, 3264};

// ---------------------------------------------------------------------------
// R10: fused prep kernel (was 5 dispatches: x->bf16, lA->bf16, 3 transposes).
// Block ranges:
//   [0,512)        : x (1024x512 f32) -> Xb bf16, float4/thread
//   [512,768)      : lA (4096x64 f32) -> lAb bf16
//   [768,1584)     : transpose ip_w  (3264x1024) -> ip_wt  (1024x3264)
//   [1584,2096)    : transpose out_w (1024x1968) -> out_wt (2048x1024, pad 0)
//   [2096,2160)    : transpose lB    (64x4096)   -> lBt    (4096x64)
// ---------------------------------------------------------------------------
__global__ __launch_bounds__(256)
void prep_misc(const float* __restrict__ x, u16* __restrict__ Xb,
               const float* __restrict__ lA, u16* __restrict__ lAb,
               const float* __restrict__ ip_w, u16* __restrict__ ip_wt,
               const float* __restrict__ out_w, u16* __restrict__ out_wt,
               const float* __restrict__ lB, u16* __restrict__ lBt) {
  __shared__ float tile[64][65];
  int b = blockIdx.x;
  const int t = threadIdx.x;
  if (b < 512) {
    const int i = b * 256 + t;
    const float4 v = ((const float4*)x)[i];
    ((ushort4*)Xb)[i] = make_ushort4(f2bf(v.x), f2bf(v.y), f2bf(v.z), f2bf(v.w));
    return;
  }
  b -= 512;
  if (b < 256) {
    const int i = b * 256 + t;
    const float4 v = ((const float4*)lA)[i];
    ((ushort4*)lAb)[i] = make_ushort4(f2bf(v.x), f2bf(v.y), f2bf(v.z), f2bf(v.w));
    return;
  }
  b -= 256;
  const float* src; u16* dst; int R, C, bx, by;
  if (b < 816)        { src = ip_w;  dst = ip_wt;  R = 3264; C = 1024; bx = b % 16; by = b / 16; }
  else if (b < 1328)  { b -= 816;  src = out_w; dst = out_wt; R = 1024; C = 1968; bx = b % 32; by = b / 32; }
  else                { b -= 1328; src = lB;    dst = lBt;    R = 64;   C = 4096; bx = b;      by = 0; }
  const int rb = by << 6, cbs = bx << 6;
  for (int i = 0; i < 16; ++i) {
    const int idx = t + (i << 8);
    const int r = idx >> 6, c = idx & 63;
    float v = 0.f;
    if (cbs + c < C) v = src[(size_t)(rb + r) * C + cbs + c];
    tile[r][c] = v;
  }
  __syncthreads();
  for (int i = 0; i < 16; ++i) {
    const int idx = t + (i << 8);
    const int c = idx >> 6, r = idx & 63;
    dst[(size_t)(cbs + c) * R + rb + r] = f2bf(tile[r][c]);
  }
}

// ---------------------------------------------------------------------------
// Implicit-GEMM conv weight scatter. R10: self-zeroing (grid 3328; each block
// zeros its own Wct row first -> drops the Wct/bias_c memset dispatches).
// ---------------------------------------------------------------------------
__global__ __launch_bounds__(256)
void build_wc(const float* w1, const float* w2, const float* w3, const float* w4,
              const float* w5, const float* w6, const float* w7, const float* w8,
              const float* __restrict__ cb,
              u16* __restrict__ Wct, float* __restrict__ bias_c) {
  const int o = blockIdx.x;
  const int t = threadIdx.x;
  u16* row = Wct + (size_t)o * 512;
  if (t < 128) *(ushort4*)(row + (t << 2)) = make_ushort4(0, 0, 0, 0);
  if (o >= 3264) {                 // padded rows: zero row + zero bias
    if (t == 0) bias_c[o] = 0.f;
    return;
  }
  __syncthreads();
  const float* ws[8] = {w1, w2, w3, w4, w5, w6, w7, w8};
  int kidx = 0;
  while (o >= c_off[kidx + 1]) ++kidx;
  const int ks = kidx + 1;
  const int s  = 8 - kidx;
  const int r  = o - c_off[kidx];
  const int f   = r / (s * s);
  const int rem = r - f * s * s;
  const int oi  = rem / s;
  const int oj  = rem - oi * s;
  const float* w = ws[kidx] + (size_t)f * 8 * ks * ks;
  const int ne = 8 * ks * ks;
  for (int e = t; e < ne; e += 256) {
    const int c  = e / (ks * ks);
    const int er = e - c * ks * ks;
    const int di = er / ks;
    const int dj = er - di * ks;
    row[((oi + di) * 8 + (oj + dj)) * 8 + c] = f2bf(w[(c * ks + di) * ks + dj]);
  }
  if (t == 0) bias_c[o] = cb[kidx * 16 + f];
}

// ---------------------------------------------------------------------------
// W_eff kernel (R8 win, ~18us): per 64x64 tile, MFMA LoRA product + masked
// combine with W + transpose through padded LDS -> coalesced Wt writes.
// ---------------------------------------------------------------------------
__global__ __launch_bounds__(256)
void weff2(const float* __restrict__ W, const u16* __restrict__ lBt,
           const u16* __restrict__ lAb, u16* __restrict__ Wt) {
  __shared__ __align__(16) u16 As_[64 * 64];
  __shared__ __align__(16) u16 Bs_[64 * 64];
  __shared__ __align__(16) float Wl[64 * 64];
  __shared__ u16 Ct[64 * 68];
  const int t = threadIdx.x;
  const int w = t >> 6, lane = t & 63;
  const int nb = blockIdx.x << 6, kb = blockIdx.y << 6;
  const int m0 = (w & 1) << 5, n0 = (w >> 1) << 5;
  const int lr = lane & 15, lq = lane >> 4;

  for (int i = 0; i < 2; ++i) {
    const int c   = (w << 7) + (i << 6) + lane;
    const int row = c >> 3;
    const int kg  = (c & 7) ^ (row & 7);
    gl_lds16(lBt + (size_t)(nb + row) * 64 + (kg << 3), (char*)As_ + c * 16);
    gl_lds16(lAb + (size_t)(kb + row) * 64 + (kg << 3), (char*)Bs_ + c * 16);
  }
  for (int i = 0; i < 4; ++i) {
    const int c   = (w << 8) + (i << 6) + lane;
    const int row = c >> 4;
    const int cc  = (c & 15) ^ (row & 15);
    gl_lds16(W + (size_t)(kb + row) * 4096 + nb + (cc << 2), (char*)Wl + c * 16);
  }
  __syncthreads();

  f32x4 acc[2][2] = {};
  for (int kk = 0; kk < 2; ++kk) {
    const int kg = (kk << 2) + lq;
    const int sw = (kg ^ (lr & 7)) << 3;
    bf16x8 af[2], bf[2];
    for (int i = 0; i < 2; ++i)
      af[i] = *(const bf16x8*)&As_[(m0 + (i << 4) + lr) * 64 + sw];
    for (int j = 0; j < 2; ++j)
      bf[j] = *(const bf16x8*)&Bs_[(n0 + (j << 4) + lr) * 64 + sw];
    for (int i = 0; i < 2; ++i)
      for (int j = 0; j < 2; ++j)
        acc[i][j] = __builtin_amdgcn_mfma_f32_16x16x32_bf16(af[i], bf[j], acc[i][j], 0, 0, 0);
  }

  for (int i = 0; i < 2; ++i) {
    for (int j = 0; j < 2; ++j) {
      const int cg  = n0 + (j << 4) + lr;
      const int rg0 = m0 + (i << 4) + (lq << 2);
      const int ch  = (rg0 >> 2) ^ (cg & 15);
      const float4 wv4 = *(const float4*)&Wl[cg * 64 + (ch << 2)];
      const float wv[4] = {wv4.x, wv4.y, wv4.z, wv4.w};
      for (int r = 0; r < 4; ++r)
        Ct[(rg0 + r) * 68 + cg] =
            (wv[r] != 0.f) ? f2bf(wv[r] + 2.0f * acc[i][j][r]) : (u16)0;
    }
  }
  __syncthreads();

  const int row = t >> 2, kp = (t & 3) << 4;
  u16* dst = Wt + (size_t)(nb + row) * 4096 + kb + kp;
  const u16* src = &Ct[row * 68 + kp];
  for (int i = 0; i < 4; ++i)
    *(ushort4*)(dst + (i << 2)) = *(const ushort4*)(src + (i << 2));
}

// ---------------------------------------------------------------------------
// bf16 MFMA GEMM, 64x128 block tile, 4 waves (32x64 each), BK=64, dbuf LDS,
// XOR-swizzled. Grid = (N/128, M/64). The workhorse (~570 TF; 32x64 wave
// tile is shape-structurally optimal at M=1024: 2 waves/SIMD, see R9 notes).
// EPI 1: relu(acc + st_in[m][n]) -> outf + outb               [recurrent]
// EPI 2: acc + bias[n] -> outf, guarded n < nvalid            [output]
// EPI 3: relu(acc + bias[n]) -> outb only                     [conv feat]
// ---------------------------------------------------------------------------
template<int EPI>
__global__ __launch_bounds__(256)
void gemm128(const u16* __restrict__ A, int lda,
             const u16* __restrict__ Bt, int ldb, int K,
             const float* __restrict__ bias,
             const float* __restrict__ st_in, int st_ld,
             float* __restrict__ outf, int outf_ld,
             u16* __restrict__ outb, int outb_ld, int nvalid) {
  __shared__ __align__(16) u16 As[2][64 * 64];
  __shared__ __align__(16) u16 Bs[2][128 * 64];
  const int t = threadIdx.x;
  const int w = t >> 6, lane = t & 63;
  const int mb = blockIdx.y << 6, nb = blockIdx.x << 7;
  const int m0 = (w & 1) << 5, n0 = (w >> 1) << 6;
  const int lr = lane & 15, lq = lane >> 4;

  f32x4 acc[2][4] = {};
  const int nk = K >> 6;

  auto stage = [&](int kt, int buf) {
    const int kb = kt << 6;
    for (int i = 0; i < 2; ++i) {
      const int c   = (w << 7) + (i << 6) + lane;
      const int row = c >> 3;
      const int kg  = (c & 7) ^ (row & 7);
      gl_lds16(A + (size_t)(mb + row) * lda + kb + (kg << 3),
               (char*)As[buf] + c * 16);
    }
    for (int i = 0; i < 4; ++i) {
      const int c   = (w << 8) + (i << 6) + lane;
      const int row = c >> 3;
      const int kg  = (c & 7) ^ (row & 7);
      gl_lds16(Bt + (size_t)(nb + row) * ldb + kb + (kg << 3),
               (char*)Bs[buf] + c * 16);
    }
  };

  stage(0, 0);
  for (int kt = 0; kt < nk; ++kt) {
    const int buf = kt & 1;
    __syncthreads();
    if (kt + 1 < nk) stage(kt + 1, buf ^ 1);
    for (int kk = 0; kk < 2; ++kk) {
      const int kg = (kk << 2) + lq;
      const int sw = (kg ^ (lr & 7)) << 3;
      bf16x8 af[2], bf[4];
      for (int i = 0; i < 2; ++i)
        af[i] = *(const bf16x8*)&As[buf][(m0 + (i << 4) + lr) * 64 + sw];
      for (int j = 0; j < 4; ++j)
        bf[j] = *(const bf16x8*)&Bs[buf][(n0 + (j << 4) + lr) * 64 + sw];
      for (int i = 0; i < 2; ++i)
        for (int j = 0; j < 4; ++j)
          acc[i][j] = __builtin_amdgcn_mfma_f32_16x16x32_bf16(af[i], bf[j], acc[i][j], 0, 0, 0);
    }
  }

  for (int i = 0; i < 2; ++i) {
    for (int j = 0; j < 4; ++j) {
      const int cg = nb + n0 + (j << 4) + lr;
      for (int r = 0; r < 4; ++r) {
        const int rg = mb + m0 + (i << 4) + (lq << 2) + r;
        float v = acc[i][j][r];
        if (EPI == 1) {
          v += st_in[(size_t)rg * st_ld + cg];
          v = v > 0.f ? v : 0.f;
          outf[(size_t)rg * outf_ld + cg] = v;
          outb[(size_t)rg * outb_ld + cg] = f2bf(v);
        } else if (EPI == 2) {
          if (cg < nvalid)
            outf[(size_t)rg * outf_ld + cg] = v + bias[cg];
        } else {
          v += bias[cg];
          v = v > 0.f ? v : 0.f;
          outb[(size_t)rg * outb_ld + cg] = f2bf(v);
        }
      }
    }
  }
}

// ---------------------------------------------------------------------------
// E-stage GEMM, split-K=2 (R9 win). z=0: 26 K-iters from 0; z=1: 25 from 1664.
// ---------------------------------------------------------------------------
__global__ __launch_bounds__(256)
void gemm_e(const u16* __restrict__ A, const u16* __restrict__ Bt,
            float* __restrict__ part) {
  __shared__ __align__(16) u16 As[2][64 * 64];
  __shared__ __align__(16) u16 Bs[2][128 * 64];
  const int t = threadIdx.x;
  const int w = t >> 6, lane = t & 63;
  const int mb = blockIdx.y << 6, nb = blockIdx.x << 7;
  const int m0 = (w & 1) << 5, n0 = (w >> 1) << 6;
  const int lr = lane & 15, lq = lane >> 4;
  const int z = blockIdx.z;
  const int k0 = z ? 1664 : 0;
  const int nk = z ? 25 : 26;

  f32x4 acc[2][4] = {};

  auto stage = [&](int kt, int buf) {
    const int kb = k0 + (kt << 6);
    for (int i = 0; i < 2; ++i) {
      const int c   = (w << 7) + (i << 6) + lane;
      const int row = c >> 3;
      const int kg  = (c & 7) ^ (row & 7);
      gl_lds16(A + (size_t)(mb + row) * 3328 + kb + (kg << 3),
               (char*)As[buf] + c * 16);
    }
    for (int i = 0; i < 4; ++i) {
      const int c   = (w << 8) + (i << 6) + lane;
      const int row = c >> 3;
      const int kg  = (c & 7) ^ (row & 7);
      gl_lds16(Bt + (size_t)(nb + row) * 3264 + kb + (kg << 3),
               (char*)Bs[buf] + c * 16);
    }
  };

  stage(0, 0);
  for (int kt = 0; kt < nk; ++kt) {
    const int buf = kt & 1;
    __syncthreads();
    if (kt + 1 < nk) stage(kt + 1, buf ^ 1);
    for (int kk = 0; kk < 2; ++kk) {
      const int kg = (kk << 2) + lq;
      const int sw = (kg ^ (lr & 7)) << 3;
      bf16x8 af[2], bf[4];
      for (int i = 0; i < 2; ++i)
        af[i] = *(const bf16x8*)&As[buf][(m0 + (i << 4) + lr) * 64 + sw];
      for (int j = 0; j < 4; ++j)
        bf[j] = *(const bf16x8*)&Bs[buf][(n0 + (j << 4) + lr) * 64 + sw];
      for (int i = 0; i < 2; ++i)
        for (int j = 0; j < 4; ++j)
          acc[i][j] = __builtin_amdgcn_mfma_f32_16x16x32_bf16(af[i], bf[j], acc[i][j], 0, 0, 0);
    }
  }

  float* dst = part + (size_t)z * 1024 * 1024;
  for (int i = 0; i < 2; ++i)
    for (int j = 0; j < 4; ++j) {
      const int cg = nb + n0 + (j << 4) + lr;
      for (int r = 0; r < 4; ++r) {
        const int rg = mb + m0 + (i << 4) + (lq << 2) + r;
        dst[(size_t)rg * 1024 + cg] = acc[i][j][r];
      }
    }
}

// ---------------------------------------------------------------------------
// E combine, R10: full 4096-wide pass. cols < 1024: relu(p0+p1+bias) dual-
// store; cols >= 1024: zero-fill (replaces the two st_f/st_b memsets).
// grid 4096 blocks, float4/thread.
// ---------------------------------------------------------------------------
__global__ __launch_bounds__(256)
void e_combine(const float* __restrict__ part, const float* __restrict__ bias,
               float* __restrict__ st_f, u16* __restrict__ st_b) {
  const int i = (blockIdx.x * 256 + threadIdx.x) << 2;
  const int row = i >> 12, col = i & 4095;
  if (col < 1024) {
    const int pi = (row << 10) + col;
    const float4 a = *(const float4*)&part[pi];
    const float4 b = *(const float4*)&part[1024 * 1024 + pi];
    const float4 bs = *(const float4*)&bias[col];
    float v[4] = {a.x + b.x + bs.x, a.y + b.y + bs.y,
                  a.z + b.z + bs.z, a.w + b.w + bs.w};
    u16 o[4];
    for (int r = 0; r < 4; ++r) {
      v[r] = v[r] > 0.f ? v[r] : 0.f;
      o[r] = f2bf(v[r]);
    }
    *(float4*)&st_f[i] = make_float4(v[0], v[1], v[2], v[3]);
    *(ushort4*)&st_b[i] = make_ushort4(o[0], o[1], o[2], o[3]);
  } else {
    *(float4*)&st_f[i] = make_float4(0.f, 0.f, 0.f, 0.f);
    *(ushort4*)&st_b[i] = make_ushort4(0, 0, 0, 0);
  }
}

// ---------------------------------------------------------------------------
extern "C" void kernel_launch(void* const* d_in, const int* in_sizes, int n_in,
                              void* d_out, int out_size, void* d_ws, size_t ws_size,
                              hipStream_t stream) {
  const float* x     = (const float*)d_in[0];
  const float* cw[8];
  for (int i = 0; i < 8; ++i) cw[i] = (const float*)d_in[1 + i];
  const float* convb = (const float*)d_in[9];
  const float* W     = (const float*)d_in[10];
  const float* lA    = (const float*)d_in[11];
  const float* lB    = (const float*)d_in[12];
  const float* ip_w  = (const float*)d_in[13];
  const float* ip_b  = (const float*)d_in[14];
  const float* out_w = (const float*)d_in[15];
  const float* out_b = (const float*)d_in[16];
  float* out = (float*)d_out;

  char* p = (char*)d_ws;
  u16* feat   = (u16*)p;  p += (size_t)1024 * 3328 * 2;   // lda 3328 (N padded)
  u16* ip_wt  = (u16*)p;  p += (size_t)1024 * 3264 * 2;
  u16* out_wt = (u16*)p;  p += (size_t)2048 * 1024 * 2;
  u16* Wt     = (u16*)p;  p += (size_t)4096 * 4096 * 2;
  float* st_f[2];
  st_f[0] = (float*)p;    p += (size_t)1024 * 4096 * 4;
  st_f[1] = (float*)p;    p += (size_t)1024 * 4096 * 4;
  u16* st_b[2];
  st_b[0] = (u16*)p;      p += (size_t)1024 * 4096 * 2;
  st_b[1] = (u16*)p;      p += (size_t)1024 * 4096 * 2;

  // Prep buffers alias st_f[1] (16 MB): all consumed before ts=1 writes it.
  char* q = (char*)st_f[1];
  u16* Xb       = (u16*)q;  q += (size_t)1024 * 512 * 2;
  u16* Wct      = (u16*)q;  q += (size_t)3328 * 512 * 2;
  float* bias_c = (float*)q; q += (size_t)3328 * 4;
  u16* lBt      = (u16*)q;  q += (size_t)4096 * 64 * 2;
  u16* lAb      = (u16*)q;  q += (size_t)4096 * 64 * 2;
  q = (char*)st_f[1] + (size_t)6 * 1024 * 1024;
  float* Epart  = (float*)q;                               // 8 MB (2 x 4 MB)

  // 1. fused prep: x/lA converts + 3 transposes
  prep_misc<<<2160, 256, 0, stream>>>(x, Xb, lA, lAb, ip_w, ip_wt,
                                      out_w, out_wt, lB, lBt);

  // 2. conv weight scatter (self-zeroing)
  build_wc<<<3328, 256, 0, stream>>>(cw[0], cw[1], cw[2], cw[3],
                                     cw[4], cw[5], cw[6], cw[7], convb, Wct, bias_c);

  // 3. W_eff
  weff2<<<dim3(64, 64), 256, 0, stream>>>(W, lBt, lAb, Wt);

  // 4. conv as MFMA GEMM
  gemm128<3><<<dim3(26, 16), 256, 0, stream>>>(Xb, 512, Wct, 512, 512,
      bias_c, nullptr, 0, nullptr, 0, feat, 3328, 3328);

  // 5-6. t=0: state = relu(E_pad), split-K E + full-width combine (zeros pad)
  gemm_e<<<dim3(8, 16, 2), 256, 0, stream>>>(feat, ip_wt, Epart);
  e_combine<<<4096, 256, 0, stream>>>(Epart, ip_b, st_f[0], st_b[0]);

  // 7-10. t=1..4: state = relu(state + state @ W_eff)
  for (int ts = 1; ts <= 4; ++ts) {
    const int cur = (ts - 1) & 1, nxt = ts & 1;
    gemm128<1><<<dim3(32, 16), 256, 0, stream>>>(st_b[cur], 4096, Wt, 4096, 4096,
        nullptr, st_f[cur], 4096, st_f[nxt], 4096, st_b[nxt], 4096, 4096);
  }

  // 11. output: state[:, 3072:] @ out_w + out_b
  gemm128<2><<<dim3(16, 16), 256, 0, stream>>>(st_b[0] + 3072, 4096, out_wt, 1024, 1024,
      out_b, nullptr, 0, out, 1968, nullptr, 0, 1968);
}